// Round 4
// baseline (1816.925 us; speedup 1.0000x reference)
//
#include <hip/hip_runtime.h>
#include <hip/hip_bf16.h>

#define N_NODES 50000
#define N_EDGES 800000
#define N_RELS 65
#define DIM 64
#define N_GRAPHS 512

#define BUCKET 64
#define NBUCKETS ((N_NODES + BUCKET - 1) / BUCKET)   // 782
#define NKEYS (NBUCKETS * N_RELS)                    // 50830
#define SCAN_BLK 512
#define NKB ((NKEYS + SCAN_BLK - 1) / SCAN_BLK)      // 100

typedef __attribute__((ext_vector_type(8))) short short8;
typedef __attribute__((ext_vector_type(4))) float f32x4;

// ================= prep: conversions =================

__global__ void conv_h_kernel(const float* __restrict__ x, __hip_bfloat16* __restrict__ y) {
    int i = blockIdx.x * 256 + threadIdx.x;
    if (i < N_NODES * DIM) y[i] = __float2bfloat16(x[i]);
}

// W f32 [r][k][n] -> Wt bf16 [r][n][k]  (B-frag friendly: contiguous in k)
__global__ void conv_wt_kernel(const float* __restrict__ W, __hip_bfloat16* __restrict__ Wt) {
    int i = blockIdx.x * 256 + threadIdx.x;
    if (i < N_RELS * DIM * DIM) {
        int r = i >> 12, rest = i & 4095;
        int n = rest >> 6, k = rest & 63;
        Wt[(size_t)r * 4096 + n * 64 + k] = __float2bfloat16(W[(size_t)r * 4096 + k * 64 + n]);
    }
}

// ================= prep: (bucket, rel) counting sort =================

__global__ void keyhist_kernel(const int* __restrict__ et, const int* __restrict__ dst,
                               int* __restrict__ khist) {
    int i = blockIdx.x * 256 + threadIdx.x;
    if (i < N_EDGES) atomicAdd(&khist[(dst[i] >> 6) * N_RELS + et[i]], 1);
}

__global__ __launch_bounds__(SCAN_BLK) void scanblk_kernel(const int* __restrict__ cnt, int n,
                                                           int* __restrict__ outv,
                                                           int* __restrict__ blk_tot) {
    __shared__ int tmp[SCAN_BLK];
    int t = threadIdx.x;
    int i = blockIdx.x * SCAN_BLK + t;
    int v = (i < n) ? cnt[i] : 0;
    tmp[t] = v;
    __syncthreads();
    for (int off = 1; off < SCAN_BLK; off <<= 1) {
        int add = (t >= off) ? tmp[t - off] : 0;
        __syncthreads();
        tmp[t] += add;
        __syncthreads();
    }
    if (i < n) outv[i] = tmp[t] - v;  // exclusive
    if (t == SCAN_BLK - 1) blk_tot[blockIdx.x] = tmp[t];
}

__global__ void scantop_kernel(int* __restrict__ blk_tot, int* __restrict__ blk_base,
                               int nb, int* __restrict__ seg_ptr) {
    if (threadIdx.x == 0 && blockIdx.x == 0) {
        int run = 0;
        for (int b = 0; b < nb; ++b) { blk_base[b] = run; run += blk_tot[b]; }
        seg_ptr[NKEYS] = N_EDGES;
    }
}

__global__ __launch_bounds__(SCAN_BLK) void scanadd_kernel(int* __restrict__ outv, int n,
                                                           const int* __restrict__ blk_base) {
    int i = blockIdx.x * SCAN_BLK + threadIdx.x;
    if (i < n) outv[i] += blk_base[blockIdx.x];
}

__global__ void scatter_epk_kernel(const int* __restrict__ et, const int* __restrict__ src,
                                   const int* __restrict__ dst, int* __restrict__ kcur,
                                   unsigned* __restrict__ epk) {
    int i = blockIdx.x * 256 + threadIdx.x;
    if (i < N_EDGES) {
        int key = (dst[i] >> 6) * N_RELS + et[i];
        int p = atomicAdd(&kcur[key], 1);
        epk[p] = (unsigned)src[i] | ((unsigned)(dst[i] & 63) << 16);
    }
}

// ================= prep: graph segments (graph_ids sorted) =================

__global__ void histgid_kernel(const int* __restrict__ gid, int* __restrict__ cnt_g) {
    int i = blockIdx.x * 256 + threadIdx.x;
    if (i < N_NODES) atomicAdd(&cnt_g[gid[i]], 1);
}

__global__ __launch_bounds__(512) void scangid_kernel(const int* __restrict__ cnt_g,
                                                      int* __restrict__ g_ptr) {
    __shared__ int tmp[512];
    int t = threadIdx.x;
    int v = (t < N_GRAPHS) ? cnt_g[t] : 0;
    tmp[t] = v;
    __syncthreads();
    for (int off = 1; off < 512; off <<= 1) {
        int add = (t >= off) ? tmp[t - off] : 0;
        __syncthreads();
        tmp[t] += add;
        __syncthreads();
    }
    if (t < N_GRAPHS) g_ptr[t] = tmp[t] - v;
}

// ================= fused RGCN layer =================
// One workgroup (4 waves) per 64-node dst bucket. Edges sorted by (bucket, rel).
// Wave w handles rel segments r = w, w+4, ... ; W[r] held as 8 MFMA B-frags
// (32 VGPRs, guaranteed register-resident). Per 16-edge tile: gather bf16 h
// rows -> per-wave LDS stage -> A-frags -> 8 MFMA -> LDS f32 atomic scatter
// into the bucket accumulator. Epilogue: bias + ReLU + bf16 store.

__global__ __launch_bounds__(256) void rgcn_fused_kernel(
    const __hip_bfloat16* __restrict__ hb, const __hip_bfloat16* __restrict__ Wt,
    const int* __restrict__ seg_ptr, const unsigned* __restrict__ epk,
    const float* __restrict__ bias, __hip_bfloat16* __restrict__ hout) {
    __shared__ float agg[BUCKET * DIM];                           // 16 KB
    __shared__ __align__(16) unsigned short stage[4][16 * 72];    // 9 KB (+8 pad/row)

    int t = threadIdx.x;
    int b = blockIdx.x;
    int w = t >> 6, lane = t & 63;
    int quad = lane >> 4, m16 = lane & 15;

    for (int i = t; i < BUCKET * DIM; i += 256) agg[i] = 0.f;
    __syncthreads();

    unsigned short* st = &stage[w][0];

    for (int r = w; r < N_RELS; r += 4) {
        int s0 = seg_ptr[b * N_RELS + r];
        int s1 = seg_ptr[b * N_RELS + r + 1];
        if (s0 >= s1) continue;

        // B-frags from Wt[r][n][k]: frag(kt,nt) lane holds B[kt*32+quad*8+j][nt*16+m16]
        short8 bf[2][4];
        const __hip_bfloat16* Wr = Wt + (size_t)r * (DIM * DIM);
        #pragma unroll
        for (int kt = 0; kt < 2; ++kt)
            #pragma unroll
            for (int nt = 0; nt < 4; ++nt)
                bf[kt][nt] = *(const short8*)(Wr + (nt * 16 + m16) * DIM + kt * 32 + quad * 8);

        for (int e0 = s0; e0 < s1; e0 += 16) {
            unsigned pk = 0;
            if (lane < 16 && e0 + lane < s1) pk = epk[e0 + lane];

            // stage 16 edge rows (128 B each), 8 rows per load instr
            #pragma unroll
            for (int half = 0; half < 2; ++half) {
                int row = (lane >> 3) + half * 8;
                unsigned pr = (unsigned)__shfl((int)pk, row);
                uint4 d; d.x = 0u; d.y = 0u; d.z = 0u; d.w = 0u;
                if (e0 + row < s1)
                    d = *(const uint4*)(hb + (size_t)(pr & 0xFFFFu) * DIM + (lane & 7) * 8);
                *(uint4*)&st[row * 72 + (lane & 7) * 8] = d;
            }

            // A-frags: A[m16][kt*32 + quad*8 + j]
            short8 a0 = *(const short8*)&st[m16 * 72 + quad * 8];
            short8 a1 = *(const short8*)&st[m16 * 72 + 32 + quad * 8];

            // dstloc for the 4 C-rows this lane owns (m = quad*4 + reg)
            int dl[4];
            #pragma unroll
            for (int reg = 0; reg < 4; ++reg)
                dl[reg] = (__shfl((int)pk, quad * 4 + reg) >> 16) & 63;

            #pragma unroll
            for (int nt = 0; nt < 4; ++nt) {
                f32x4 acc = {0.f, 0.f, 0.f, 0.f};
                acc = __builtin_amdgcn_mfma_f32_16x16x32_bf16(a0, bf[0][nt], acc, 0, 0, 0);
                acc = __builtin_amdgcn_mfma_f32_16x16x32_bf16(a1, bf[1][nt], acc, 0, 0, 0);
                #pragma unroll
                for (int reg = 0; reg < 4; ++reg)
                    atomicAdd(&agg[dl[reg] * DIM + nt * 16 + m16], acc[reg]);
            }
        }
    }
    __syncthreads();

    int n0 = b * BUCKET;
    for (int i = t; i < BUCKET * DIM; i += 256) {
        int nl = i >> 6, d = i & 63;
        int n = n0 + nl;
        if (n < N_NODES) {
            float v = agg[i] + bias[d];
            hout[(size_t)n * DIM + d] = __float2bfloat16(v > 0.f ? v : 0.f);
        }
    }
}

// ================= graph sum-pool (segmented, bf16 h) =================

__global__ __launch_bounds__(256) void pool_seg_kernel(
    const __hip_bfloat16* __restrict__ h, const int* __restrict__ g_ptr,
    const int* __restrict__ cnt_g, float* __restrict__ g) {
    int wave = blockIdx.x * 4 + (threadIdx.x >> 6);
    int lane = threadIdx.x & 63;
    if (wave >= N_GRAPHS) return;
    int j0 = g_ptr[wave];
    int n  = cnt_g[wave];
    float a0 = 0.f, a1 = 0.f;
    int j = 0;
    for (; j + 1 < n; j += 2) {
        a0 += __bfloat162float(h[(size_t)(j0 + j) * DIM + lane]);
        a1 += __bfloat162float(h[(size_t)(j0 + j + 1) * DIM + lane]);
    }
    if (j < n) a0 += __bfloat162float(h[(size_t)(j0 + j) * DIM + lane]);
    g[(size_t)wave * DIM + lane] = a0 + a1;
}

// ================= fused FC x3 + prediction head =================

__global__ __launch_bounds__(256) void fc_kernel(
    const float* __restrict__ g,
    const float* __restrict__ W1, const float* __restrict__ b1,
    const float* __restrict__ W2, const float* __restrict__ b2,
    const float* __restrict__ W3, const float* __restrict__ b3,
    const float* __restrict__ pW, const float* __restrict__ pb,
    float* __restrict__ out) {
    int wave = blockIdx.x * 4 + (threadIdx.x >> 6);
    int lane = threadIdx.x & 63;
    if (wave >= N_GRAPHS) return;

    float v = g[(size_t)wave * DIM + lane];

    const float* Ws[3] = {W1, W2, W3};
    const float* bs[3] = {b1, b2, b3};
    for (int l = 0; l < 3; ++l) {
        float acc = bs[l][lane];
        const float* __restrict__ Wl = Ws[l];
        #pragma unroll
        for (int d = 0; d < DIM; ++d)
            acc += __shfl(v, d) * Wl[d * DIM + lane];
        v = acc > 0.f ? acc : 0.f;
    }

    float p0 = v * pW[lane * 2 + 0];
    float p1 = v * pW[lane * 2 + 1];
    #pragma unroll
    for (int off = 32; off > 0; off >>= 1) {
        p0 += __shfl_down(p0, off);
        p1 += __shfl_down(p1, off);
    }
    if (lane == 0) {
        out[wave * 2 + 0] = p0 + pb[0];
        out[wave * 2 + 1] = p1 + pb[1];
    }
}

// ================= launch =================

extern "C" void kernel_launch(void* const* d_in, const int* in_sizes, int n_in,
                              void* d_out, int out_size, void* d_ws, size_t ws_size,
                              hipStream_t stream) {
    const float* node_feats = (const float*)d_in[0];
    const int*   etypes     = (const int*)d_in[1];
    const int*   src        = (const int*)d_in[2];
    const int*   dst        = (const int*)d_in[3];
    const int*   graph_ids  = (const int*)d_in[4];
    const float* W1 = (const float*)d_in[5];
    const float* b1 = (const float*)d_in[6];
    const float* W2 = (const float*)d_in[7];
    const float* b2 = (const float*)d_in[8];
    const float* W3 = (const float*)d_in[9];
    const float* b3 = (const float*)d_in[10];
    const float* fcW1 = (const float*)d_in[11];
    const float* fcb1 = (const float*)d_in[12];
    const float* fcW2 = (const float*)d_in[13];
    const float* fcb2 = (const float*)d_in[14];
    const float* fcW3 = (const float*)d_in[15];
    const float* fcb3 = (const float*)d_in[16];
    const float* pW = (const float*)d_in[17];
    const float* pb = (const float*)d_in[18];
    float* out = (float*)d_out;

    // workspace carve-up (256B aligned)
    char* p = (char*)d_ws;
    auto alloc = [&](size_t bytes) -> void* {
        void* r = (void*)p;
        p += (bytes + 255) & ~(size_t)255;
        return r;
    };
    int* khist    = (int*)alloc((size_t)NKEYS * sizeof(int));
    int* seg_ptr  = (int*)alloc((size_t)(NKEYS + 1) * sizeof(int));
    int* kcur     = (int*)alloc((size_t)NKEYS * sizeof(int));
    int* blk_tot  = (int*)alloc(NKB * sizeof(int));
    int* blk_base = (int*)alloc(NKB * sizeof(int));
    unsigned* epk = (unsigned*)alloc((size_t)N_EDGES * sizeof(unsigned));
    int* cnt_g    = (int*)alloc(N_GRAPHS * sizeof(int));
    int* g_ptr    = (int*)alloc(N_GRAPHS * sizeof(int));
    float* g      = (float*)alloc((size_t)N_GRAPHS * DIM * sizeof(float));
    __hip_bfloat16* hb0 = (__hip_bfloat16*)alloc((size_t)N_NODES * DIM * sizeof(__hip_bfloat16));
    __hip_bfloat16* hb1 = (__hip_bfloat16*)alloc((size_t)N_NODES * DIM * sizeof(__hip_bfloat16));
    __hip_bfloat16* Wt1 = (__hip_bfloat16*)alloc((size_t)N_RELS * DIM * DIM * sizeof(__hip_bfloat16));
    __hip_bfloat16* Wt2 = (__hip_bfloat16*)alloc((size_t)N_RELS * DIM * DIM * sizeof(__hip_bfloat16));
    __hip_bfloat16* Wt3 = (__hip_bfloat16*)alloc((size_t)N_RELS * DIM * DIM * sizeof(__hip_bfloat16));

    const int EBLK = (N_EDGES + 255) / 256;              // 3125
    const int HBLK = (N_NODES * DIM + 255) / 256;        // 12500
    const int WBLK = (N_RELS * DIM * DIM + 255) / 256;   // 1040
    const int NBLK256 = (N_NODES + 255) / 256;           // 196

    // ---- prep: conversions ----
    conv_h_kernel<<<HBLK, 256, 0, stream>>>(node_feats, hb0);
    conv_wt_kernel<<<WBLK, 256, 0, stream>>>(W1, Wt1);
    conv_wt_kernel<<<WBLK, 256, 0, stream>>>(W2, Wt2);
    conv_wt_kernel<<<WBLK, 256, 0, stream>>>(W3, Wt3);

    // ---- prep: (bucket, rel) sort ----
    hipMemsetAsync(khist, 0, (size_t)NKEYS * sizeof(int), stream);
    keyhist_kernel<<<EBLK, 256, 0, stream>>>(etypes, dst, khist);
    scanblk_kernel<<<NKB, SCAN_BLK, 0, stream>>>(khist, NKEYS, seg_ptr, blk_tot);
    scantop_kernel<<<1, 64, 0, stream>>>(blk_tot, blk_base, NKB, seg_ptr);
    scanadd_kernel<<<NKB, SCAN_BLK, 0, stream>>>(seg_ptr, NKEYS, blk_base);
    hipMemcpyAsync(kcur, seg_ptr, (size_t)NKEYS * sizeof(int),
                   hipMemcpyDeviceToDevice, stream);
    scatter_epk_kernel<<<EBLK, 256, 0, stream>>>(etypes, src, dst, kcur, epk);

    // ---- prep: graph segments ----
    hipMemsetAsync(cnt_g, 0, N_GRAPHS * sizeof(int), stream);
    histgid_kernel<<<NBLK256, 256, 0, stream>>>(graph_ids, cnt_g);
    scangid_kernel<<<1, 512, 0, stream>>>(cnt_g, g_ptr);

    // ---- 3 fused RGCN layers ----
    rgcn_fused_kernel<<<NBUCKETS, 256, 0, stream>>>(hb0, Wt1, seg_ptr, epk, b1, hb1);
    rgcn_fused_kernel<<<NBUCKETS, 256, 0, stream>>>(hb1, Wt2, seg_ptr, epk, b2, hb0);
    rgcn_fused_kernel<<<NBUCKETS, 256, 0, stream>>>(hb0, Wt3, seg_ptr, epk, b3, hb1);

    // ---- pool + FC head ----
    pool_seg_kernel<<<(N_GRAPHS + 3) / 4, 256, 0, stream>>>(hb1, g_ptr, cnt_g, g);
    fc_kernel<<<(N_GRAPHS + 3) / 4, 256, 0, stream>>>(g, fcW1, fcb1, fcW2, fcb2,
                                                      fcW3, fcb3, pW, pb, out);
}

// Round 5
// 499.086 us; speedup vs baseline: 3.6405x; 3.6405x over previous
//
#include <hip/hip_runtime.h>
#include <hip/hip_bf16.h>

#define N_NODES 50000
#define N_EDGES 800000
#define N_RELS 65
#define DIM 64
#define N_GRAPHS 512

#define SORT_BLOCKS 256
#define CHUNK ((N_EDGES + SORT_BLOCKS - 1) / SORT_BLOCKS)  // 3125

#define SCAN_BLK 512
#define NSCAN_BLKS ((N_NODES + SCAN_BLK - 1) / SCAN_BLK)   // 98

#define MSG_BLOCKS 1024
#define NWAVES (MSG_BLOCKS * 4)

typedef __attribute__((ext_vector_type(8))) short short8;
typedef __attribute__((ext_vector_type(4))) float f32x4;

// ================= prep: conversions =================

__global__ void conv_h_kernel(const float* __restrict__ x, __hip_bfloat16* __restrict__ y) {
    int i = blockIdx.x * 256 + threadIdx.x;
    if (i < N_NODES * DIM) y[i] = __float2bfloat16(x[i]);
}

// W f32 [r][k][n] -> Wt bf16 [r][n][k]  (B-frag friendly: contiguous in k)
__global__ void conv_wt_kernel(const float* __restrict__ W, __hip_bfloat16* __restrict__ Wt) {
    int i = blockIdx.x * 256 + threadIdx.x;
    if (i < N_RELS * DIM * DIM) {
        int r = i >> 12, rest = i & 4095;
        int n = rest >> 6, k = rest & 63;
        Wt[(size_t)r * 4096 + n * 64 + k] = __float2bfloat16(W[(size_t)r * 4096 + k * 64 + n]);
    }
}

// ================= prep: rel-sort (block-stable counting sort) =================

__global__ __launch_bounds__(256) void hist2_kernel(const int* __restrict__ et,
                                                    int* __restrict__ blk_hist) {
    __shared__ int lh[N_RELS];
    int t = threadIdx.x, b = blockIdx.x;
    if (t < N_RELS) lh[t] = 0;
    __syncthreads();
    int lo = b * CHUNK;
    int hi = lo + CHUNK; if (hi > N_EDGES) hi = N_EDGES;
    for (int i = lo + t; i < hi; i += 256) atomicAdd(&lh[et[i]], 1);
    __syncthreads();
    if (t < N_RELS) blk_hist[b * N_RELS + t] = lh[t];
}

// column scan over blocks + relation bases; emits rel_ptr[66] and tile_base[66]
__global__ __launch_bounds__(128) void relscan_kernel(const int* __restrict__ blk_hist,
                                                      int* __restrict__ blk_off,
                                                      int* __restrict__ rel_ptr,
                                                      int* __restrict__ tile_base) {
    __shared__ int total[N_RELS];
    __shared__ int rel_base[N_RELS];
    int r = threadIdx.x;
    if (r < N_RELS) {
        int run = 0;
        for (int b = 0; b < SORT_BLOCKS; ++b) {
            int idx = b * N_RELS + r;
            int v = blk_hist[idx];
            blk_off[idx] = run;
            run += v;
        }
        total[r] = run;
    }
    __syncthreads();
    if (r == 0) {
        int s = 0, tt = 0;
        for (int q = 0; q < N_RELS; ++q) {
            rel_base[q] = s; s += total[q];
            tile_base[q] = tt; tt += (total[q] + 15) >> 4;
        }
        rel_ptr[N_RELS] = N_EDGES;
        tile_base[N_RELS] = tt;
    }
    __syncthreads();
    if (r < N_RELS) {
        int base = rel_base[r];
        rel_ptr[r] = base;
        for (int b = 0; b < SORT_BLOCKS; ++b) blk_off[b * N_RELS + r] += base;
    }
}

__global__ __launch_bounds__(256) void scatter2_kernel(
    const int* __restrict__ et, const int* __restrict__ src,
    const int* __restrict__ dst, const int* __restrict__ blk_off,
    int* __restrict__ src_s, int* __restrict__ dst_s) {
    __shared__ int cur[N_RELS];
    int t = threadIdx.x, b = blockIdx.x;
    if (t < N_RELS) cur[t] = blk_off[b * N_RELS + t];
    __syncthreads();
    int lo = b * CHUNK;
    int hi = lo + CHUNK; if (hi > N_EDGES) hi = N_EDGES;
    for (int i = lo + t; i < hi; i += 256) {
        int r = et[i];
        int p = atomicAdd(&cur[r], 1);
        src_s[p] = src[i];
        dst_s[p] = dst[i];
    }
}

// ================= prep: dst CSR =================

__global__ void histdst_kernel(const int* __restrict__ dst, int* __restrict__ cnt_d) {
    int i = blockIdx.x * 256 + threadIdx.x;
    if (i < N_EDGES) atomicAdd(&cnt_d[dst[i]], 1);
}

__global__ __launch_bounds__(SCAN_BLK) void scanblk_kernel(const int* __restrict__ cnt,
                                                           int* __restrict__ outv,
                                                           int* __restrict__ blk_tot) {
    __shared__ int tmp[SCAN_BLK];
    int t = threadIdx.x;
    int i = blockIdx.x * SCAN_BLK + t;
    int v = (i < N_NODES) ? cnt[i] : 0;
    tmp[t] = v;
    __syncthreads();
    for (int off = 1; off < SCAN_BLK; off <<= 1) {
        int add = (t >= off) ? tmp[t - off] : 0;
        __syncthreads();
        tmp[t] += add;
        __syncthreads();
    }
    if (i < N_NODES) outv[i] = tmp[t] - v;  // exclusive
    if (t == SCAN_BLK - 1) blk_tot[blockIdx.x] = tmp[t];
}

__global__ void scantop_kernel(int* __restrict__ blk_tot, int* __restrict__ blk_base) {
    if (threadIdx.x == 0 && blockIdx.x == 0) {
        int run = 0;
        for (int b = 0; b < NSCAN_BLKS; ++b) { blk_base[b] = run; run += blk_tot[b]; }
    }
}

__global__ __launch_bounds__(SCAN_BLK) void scanadd_kernel(int* __restrict__ outv,
                                                           const int* __restrict__ blk_base) {
    int i = blockIdx.x * SCAN_BLK + threadIdx.x;
    if (i < N_NODES) outv[i] += blk_base[blockIdx.x];
}

// rank each rel-sorted edge within its dst bin -> dst-sorted slot
__global__ void dpos_kernel(const int* __restrict__ dst_s, int* __restrict__ cursor,
                            int* __restrict__ dpos) {
    int i = blockIdx.x * 256 + threadIdx.x;
    if (i < N_EDGES) dpos[i] = atomicAdd(&cursor[dst_s[i]], 1);
}

// ================= prep: graph segments (graph_ids sorted) =================

__global__ void histgid_kernel(const int* __restrict__ gid, int* __restrict__ cnt_g) {
    int i = blockIdx.x * 256 + threadIdx.x;
    if (i < N_NODES) atomicAdd(&cnt_g[gid[i]], 1);
}

__global__ __launch_bounds__(512) void scangid_kernel(const int* __restrict__ cnt_g,
                                                      int* __restrict__ g_ptr) {
    __shared__ int tmp[512];
    int t = threadIdx.x;
    int v = (t < N_GRAPHS) ? cnt_g[t] : 0;
    tmp[t] = v;
    __syncthreads();
    for (int off = 1; off < 512; off <<= 1) {
        int add = (t >= off) ? tmp[t - off] : 0;
        __syncthreads();
        tmp[t] += add;
        __syncthreads();
    }
    if (t < N_GRAPHS) g_ptr[t] = tmp[t] - v;
}

// ================= phase 1: MFMA message kernel =================
// Rel-sorted edges split into 16-edge tiles (tiles never cross relations;
// tile->rel via tile_base). 4096 waves grid-stride contiguous tile chunks:
// W[r] loaded once per relation-chunk into 8 short8 B-frags (32 VGPRs,
// register-resident — R4-proven). Per tile: gather 16 bf16 h rows -> LDS ->
// A-frags -> 8 MFMA -> C transposed through LDS -> coalesced 128B bf16 row
// stores into dst-sorted slots (dpos). No atomics.

__global__ __launch_bounds__(256) void msg_mfma_kernel(
    const __hip_bfloat16* __restrict__ hb, const __hip_bfloat16* __restrict__ Wt,
    const int* __restrict__ rel_ptr, const int* __restrict__ tile_base,
    const int* __restrict__ src_s, const int* __restrict__ dpos,
    __hip_bfloat16* __restrict__ msg) {
    __shared__ __align__(16) unsigned short stA[4][16 * 72];  // bf16 A stage, +8 pad
    __shared__ __align__(16) float stC[4][16 * 68];           // f32 C stage, +4 pad

    int t = threadIdx.x;
    int w = t >> 6, lane = t & 63;
    int quad = lane >> 4, m16 = lane & 15;
    int wave = blockIdx.x * 4 + w;

    int ntiles = tile_base[N_RELS];
    int tpw = (ntiles + NWAVES - 1) / NWAVES;
    int T = wave * tpw;
    int T1 = T + tpw; if (T1 > ntiles) T1 = ntiles;
    if (T >= T1) return;

    unsigned short* sa = &stA[w][0];
    float* sc = &stC[w][0];

    int r = 0;
    while (T >= tile_base[r + 1]) ++r;

    while (T < T1) {
        // relation chunk [T, chunk_end)
        int chunk_end = tile_base[r + 1]; if (chunk_end > T1) chunk_end = T1;
        int seg_end = rel_ptr[r + 1];

        // B-frags: lane holds B[k=kt*32+quad*8+j][n=nt*16+m16] from Wt[r][n][k]
        const __hip_bfloat16* Wr = Wt + (size_t)r * (DIM * DIM);
        short8 bf00 = *(const short8*)(Wr + (0 * 16 + m16) * DIM + 0 * 32 + quad * 8);
        short8 bf01 = *(const short8*)(Wr + (1 * 16 + m16) * DIM + 0 * 32 + quad * 8);
        short8 bf02 = *(const short8*)(Wr + (2 * 16 + m16) * DIM + 0 * 32 + quad * 8);
        short8 bf03 = *(const short8*)(Wr + (3 * 16 + m16) * DIM + 0 * 32 + quad * 8);
        short8 bf10 = *(const short8*)(Wr + (0 * 16 + m16) * DIM + 1 * 32 + quad * 8);
        short8 bf11 = *(const short8*)(Wr + (1 * 16 + m16) * DIM + 1 * 32 + quad * 8);
        short8 bf12 = *(const short8*)(Wr + (2 * 16 + m16) * DIM + 1 * 32 + quad * 8);
        short8 bf13 = *(const short8*)(Wr + (3 * 16 + m16) * DIM + 1 * 32 + quad * 8);

        for (; T < chunk_end; ++T) {
            int e0 = rel_ptr[r] + (T - tile_base[r]) * 16;
            int rows = seg_end - e0; if (rows > 16) rows = 16;

            int sv = 0, dp = 0;
            if (lane < rows) { sv = src_s[e0 + lane]; dp = dpos[e0 + lane]; }

            // stage 16 rows (128 B each), 8 rows per pass
            #pragma unroll
            for (int half = 0; half < 2; ++half) {
                int row = (lane >> 3) + half * 8;
                int s = __shfl(sv, row);
                uint4 d; d.x = 0u; d.y = 0u; d.z = 0u; d.w = 0u;
                if (row < rows)
                    d = *(const uint4*)(hb + (size_t)s * DIM + (lane & 7) * 8);
                *(uint4*)&sa[row * 72 + (lane & 7) * 8] = d;
            }

            // A-frags: A[m16][kt*32 + quad*8 + j]
            short8 a0 = *(const short8*)&sa[m16 * 72 + quad * 8];
            short8 a1 = *(const short8*)&sa[m16 * 72 + 32 + quad * 8];

            f32x4 c0 = {0.f, 0.f, 0.f, 0.f}, c1 = c0, c2 = c0, c3 = c0;
            c0 = __builtin_amdgcn_mfma_f32_16x16x32_bf16(a0, bf00, c0, 0, 0, 0);
            c1 = __builtin_amdgcn_mfma_f32_16x16x32_bf16(a0, bf01, c1, 0, 0, 0);
            c2 = __builtin_amdgcn_mfma_f32_16x16x32_bf16(a0, bf02, c2, 0, 0, 0);
            c3 = __builtin_amdgcn_mfma_f32_16x16x32_bf16(a0, bf03, c3, 0, 0, 0);
            c0 = __builtin_amdgcn_mfma_f32_16x16x32_bf16(a1, bf10, c0, 0, 0, 0);
            c1 = __builtin_amdgcn_mfma_f32_16x16x32_bf16(a1, bf11, c1, 0, 0, 0);
            c2 = __builtin_amdgcn_mfma_f32_16x16x32_bf16(a1, bf12, c2, 0, 0, 0);
            c3 = __builtin_amdgcn_mfma_f32_16x16x32_bf16(a1, bf13, c3, 0, 0, 0);

            // C -> LDS (row = quad*4+reg, col = nt*16+m16)
            #pragma unroll
            for (int reg = 0; reg < 4; ++reg) {
                int rr = (quad * 4 + reg) * 68 + m16;
                sc[rr +  0] = c0[reg];
                sc[rr + 16] = c1[reg];
                sc[rr + 32] = c2[reg];
                sc[rr + 48] = c3[reg];
            }

            // read back rows, pack bf16, coalesced store (4 lanes / row)
            int orow = lane >> 2;
            if (orow < rows) {
                int c0i = (lane & 3) * 16;
                float vs[16];
                *(f32x4*)&vs[0]  = *(const f32x4*)&sc[orow * 68 + c0i + 0];
                *(f32x4*)&vs[4]  = *(const f32x4*)&sc[orow * 68 + c0i + 4];
                *(f32x4*)&vs[8]  = *(const f32x4*)&sc[orow * 68 + c0i + 8];
                *(f32x4*)&vs[12] = *(const f32x4*)&sc[orow * 68 + c0i + 12];
                unsigned short us[16];
                #pragma unroll
                for (int i = 0; i < 16; ++i)
                    us[i] = __hip_bfloat16_raw(__float2bfloat16(vs[i])).x;
                int dprow = __shfl(dp, orow);
                __hip_bfloat16* dst = msg + (size_t)dprow * DIM + c0i;
                *(uint4*)dst = *(const uint4*)&us[0];
                *(uint4*)(dst + 8) = *(const uint4*)&us[8];
            }
        }
        ++r;
        while (T < T1 && T >= tile_base[r + 1]) ++r;  // skip empty relations
    }
}

// ================= phase 2: pull-aggregate + bias + ReLU (bf16 out) =================

__global__ __launch_bounds__(256) void agg_kernel(
    const __hip_bfloat16* __restrict__ msg, const int* __restrict__ row_ptr,
    const int* __restrict__ cnt_d, const float* __restrict__ b,
    __hip_bfloat16* __restrict__ hout) {
    int wave = blockIdx.x * 4 + (threadIdx.x >> 6);
    int lane = threadIdx.x & 63;
    if (wave >= N_NODES) return;
    int j0 = row_ptr[wave];
    int n  = cnt_d[wave];
    float a0 = 0.f, a1 = 0.f, a2 = 0.f, a3 = 0.f;
    int j = 0;
    for (; j + 3 < n; j += 4) {
        a0 += __bfloat162float(msg[(size_t)(j0 + j + 0) * DIM + lane]);
        a1 += __bfloat162float(msg[(size_t)(j0 + j + 1) * DIM + lane]);
        a2 += __bfloat162float(msg[(size_t)(j0 + j + 2) * DIM + lane]);
        a3 += __bfloat162float(msg[(size_t)(j0 + j + 3) * DIM + lane]);
    }
    for (; j < n; ++j)
        a0 += __bfloat162float(msg[(size_t)(j0 + j) * DIM + lane]);
    float v = ((a0 + a1) + (a2 + a3)) + b[lane];
    hout[(size_t)wave * DIM + lane] = __float2bfloat16(v > 0.f ? v : 0.f);
}

// ================= graph sum-pool (segmented, bf16 h) =================

__global__ __launch_bounds__(256) void pool_seg_kernel(
    const __hip_bfloat16* __restrict__ h, const int* __restrict__ g_ptr,
    const int* __restrict__ cnt_g, float* __restrict__ g) {
    int wave = blockIdx.x * 4 + (threadIdx.x >> 6);
    int lane = threadIdx.x & 63;
    if (wave >= N_GRAPHS) return;
    int j0 = g_ptr[wave];
    int n  = cnt_g[wave];
    float a0 = 0.f, a1 = 0.f;
    int j = 0;
    for (; j + 1 < n; j += 2) {
        a0 += __bfloat162float(h[(size_t)(j0 + j) * DIM + lane]);
        a1 += __bfloat162float(h[(size_t)(j0 + j + 1) * DIM + lane]);
    }
    if (j < n) a0 += __bfloat162float(h[(size_t)(j0 + j) * DIM + lane]);
    g[(size_t)wave * DIM + lane] = a0 + a1;
}

// ================= fused FC x3 + prediction head =================

__global__ __launch_bounds__(256) void fc_kernel(
    const float* __restrict__ g,
    const float* __restrict__ W1, const float* __restrict__ b1,
    const float* __restrict__ W2, const float* __restrict__ b2,
    const float* __restrict__ W3, const float* __restrict__ b3,
    const float* __restrict__ pW, const float* __restrict__ pb,
    float* __restrict__ out) {
    int wave = blockIdx.x * 4 + (threadIdx.x >> 6);
    int lane = threadIdx.x & 63;
    if (wave >= N_GRAPHS) return;

    float v = g[(size_t)wave * DIM + lane];

    const float* Ws[3] = {W1, W2, W3};
    const float* bs[3] = {b1, b2, b3};
    for (int l = 0; l < 3; ++l) {
        float acc = bs[l][lane];
        const float* __restrict__ Wl = Ws[l];
        #pragma unroll
        for (int d = 0; d < DIM; ++d)
            acc += __shfl(v, d) * Wl[d * DIM + lane];
        v = acc > 0.f ? acc : 0.f;
    }

    float p0 = v * pW[lane * 2 + 0];
    float p1 = v * pW[lane * 2 + 1];
    #pragma unroll
    for (int off = 32; off > 0; off >>= 1) {
        p0 += __shfl_down(p0, off);
        p1 += __shfl_down(p1, off);
    }
    if (lane == 0) {
        out[wave * 2 + 0] = p0 + pb[0];
        out[wave * 2 + 1] = p1 + pb[1];
    }
}

// ================= launch =================

extern "C" void kernel_launch(void* const* d_in, const int* in_sizes, int n_in,
                              void* d_out, int out_size, void* d_ws, size_t ws_size,
                              hipStream_t stream) {
    const float* node_feats = (const float*)d_in[0];
    const int*   etypes     = (const int*)d_in[1];
    const int*   src        = (const int*)d_in[2];
    const int*   dst        = (const int*)d_in[3];
    const int*   graph_ids  = (const int*)d_in[4];
    const float* W1 = (const float*)d_in[5];
    const float* b1 = (const float*)d_in[6];
    const float* W2 = (const float*)d_in[7];
    const float* b2 = (const float*)d_in[8];
    const float* W3 = (const float*)d_in[9];
    const float* b3 = (const float*)d_in[10];
    const float* fcW1 = (const float*)d_in[11];
    const float* fcb1 = (const float*)d_in[12];
    const float* fcW2 = (const float*)d_in[13];
    const float* fcb2 = (const float*)d_in[14];
    const float* fcW3 = (const float*)d_in[15];
    const float* fcb3 = (const float*)d_in[16];
    const float* pW = (const float*)d_in[17];
    const float* pb = (const float*)d_in[18];
    float* out = (float*)d_out;

    // workspace carve-up (256B aligned)
    char* p = (char*)d_ws;
    auto alloc = [&](size_t bytes) -> void* {
        void* r = (void*)p;
        p += (bytes + 255) & ~(size_t)255;
        return r;
    };
    int* blk_hist  = (int*)alloc((size_t)SORT_BLOCKS * N_RELS * sizeof(int));
    int* blk_off   = (int*)alloc((size_t)SORT_BLOCKS * N_RELS * sizeof(int));
    int* rel_ptr   = (int*)alloc((N_RELS + 1) * sizeof(int));
    int* tile_base = (int*)alloc((N_RELS + 1) * sizeof(int));
    int* src_s     = (int*)alloc((size_t)N_EDGES * sizeof(int));
    int* dst_s     = (int*)alloc((size_t)N_EDGES * sizeof(int));
    int* dpos      = (int*)alloc((size_t)N_EDGES * sizeof(int));
    int* cnt_d     = (int*)alloc((size_t)N_NODES * sizeof(int));
    int* row_ptr   = (int*)alloc((size_t)N_NODES * sizeof(int));
    int* cursor_d  = (int*)alloc((size_t)N_NODES * sizeof(int));
    int* blk_tot   = (int*)alloc(NSCAN_BLKS * sizeof(int));
    int* blk_base  = (int*)alloc(NSCAN_BLKS * sizeof(int));
    int* cnt_g     = (int*)alloc(N_GRAPHS * sizeof(int));
    int* g_ptr     = (int*)alloc(N_GRAPHS * sizeof(int));
    float* g       = (float*)alloc((size_t)N_GRAPHS * DIM * sizeof(float));
    __hip_bfloat16* hb0 = (__hip_bfloat16*)alloc((size_t)N_NODES * DIM * sizeof(__hip_bfloat16));
    __hip_bfloat16* hb1 = (__hip_bfloat16*)alloc((size_t)N_NODES * DIM * sizeof(__hip_bfloat16));
    __hip_bfloat16* Wt1 = (__hip_bfloat16*)alloc((size_t)N_RELS * DIM * DIM * sizeof(__hip_bfloat16));
    __hip_bfloat16* Wt2 = (__hip_bfloat16*)alloc((size_t)N_RELS * DIM * DIM * sizeof(__hip_bfloat16));
    __hip_bfloat16* Wt3 = (__hip_bfloat16*)alloc((size_t)N_RELS * DIM * DIM * sizeof(__hip_bfloat16));
    __hip_bfloat16* msg = (__hip_bfloat16*)alloc((size_t)N_EDGES * DIM * sizeof(__hip_bfloat16));

    const int EBLK = (N_EDGES + 255) / 256;              // 3125
    const int HBLK = (N_NODES * DIM + 255) / 256;        // 12500
    const int WBLK = (N_RELS * DIM * DIM + 255) / 256;   // 1040
    const int NBLK256 = (N_NODES + 255) / 256;           // 196
    const int AGG_BLOCKS = (N_NODES + 3) / 4;            // 12500

    // ---- prep: conversions ----
    conv_h_kernel<<<HBLK, 256, 0, stream>>>(node_feats, hb0);
    conv_wt_kernel<<<WBLK, 256, 0, stream>>>(W1, Wt1);
    conv_wt_kernel<<<WBLK, 256, 0, stream>>>(W2, Wt2);
    conv_wt_kernel<<<WBLK, 256, 0, stream>>>(W3, Wt3);

    // ---- prep: rel-sort ----
    hist2_kernel<<<SORT_BLOCKS, 256, 0, stream>>>(etypes, blk_hist);
    relscan_kernel<<<1, 128, 0, stream>>>(blk_hist, blk_off, rel_ptr, tile_base);
    scatter2_kernel<<<SORT_BLOCKS, 256, 0, stream>>>(etypes, src, dst, blk_off,
                                                     src_s, dst_s);

    // ---- prep: dst CSR ----
    hipMemsetAsync(cnt_d, 0, (size_t)N_NODES * sizeof(int), stream);
    histdst_kernel<<<EBLK, 256, 0, stream>>>(dst, cnt_d);
    scanblk_kernel<<<NSCAN_BLKS, SCAN_BLK, 0, stream>>>(cnt_d, row_ptr, blk_tot);
    scantop_kernel<<<1, 64, 0, stream>>>(blk_tot, blk_base);
    scanadd_kernel<<<NSCAN_BLKS, SCAN_BLK, 0, stream>>>(row_ptr, blk_base);
    hipMemcpyAsync(cursor_d, row_ptr, (size_t)N_NODES * sizeof(int),
                   hipMemcpyDeviceToDevice, stream);
    dpos_kernel<<<EBLK, 256, 0, stream>>>(dst_s, cursor_d, dpos);

    // ---- prep: graph segments ----
    hipMemsetAsync(cnt_g, 0, N_GRAPHS * sizeof(int), stream);
    histgid_kernel<<<NBLK256, 256, 0, stream>>>(graph_ids, cnt_g);
    scangid_kernel<<<1, 512, 0, stream>>>(cnt_g, g_ptr);

    // ---- 3 RGCN layers ----
    msg_mfma_kernel<<<MSG_BLOCKS, 256, 0, stream>>>(hb0, Wt1, rel_ptr, tile_base,
                                                    src_s, dpos, msg);
    agg_kernel<<<AGG_BLOCKS, 256, 0, stream>>>(msg, row_ptr, cnt_d, b1, hb1);

    msg_mfma_kernel<<<MSG_BLOCKS, 256, 0, stream>>>(hb1, Wt2, rel_ptr, tile_base,
                                                    src_s, dpos, msg);
    agg_kernel<<<AGG_BLOCKS, 256, 0, stream>>>(msg, row_ptr, cnt_d, b2, hb0);

    msg_mfma_kernel<<<MSG_BLOCKS, 256, 0, stream>>>(hb0, Wt3, rel_ptr, tile_base,
                                                    src_s, dpos, msg);
    agg_kernel<<<AGG_BLOCKS, 256, 0, stream>>>(msg, row_ptr, cnt_d, b3, hb1);

    // ---- pool + FC head ----
    pool_seg_kernel<<<(N_GRAPHS + 3) / 4, 256, 0, stream>>>(hb1, g_ptr, cnt_g, g);
    fc_kernel<<<(N_GRAPHS + 3) / 4, 256, 0, stream>>>(g, fcW1, fcb1, fcW2, fcb2,
                                                      fcW3, fcb3, pW, pb, out);
}

// Round 6
// 451.991 us; speedup vs baseline: 4.0198x; 1.1042x over previous
//
#include <hip/hip_runtime.h>
#include <hip/hip_bf16.h>

#define N_NODES 50000
#define N_EDGES 800000
#define N_RELS 65
#define DIM 64
#define N_GRAPHS 512

#define SORT_BLOCKS 256
#define CHUNK ((N_EDGES + SORT_BLOCKS - 1) / SORT_BLOCKS)  // 3125

#define SCAN_BLK 512
#define NSCAN_BLKS ((N_NODES + SCAN_BLK - 1) / SCAN_BLK)   // 98

#define MSG_BLOCKS 1024
#define NWAVES (MSG_BLOCKS * 4)

typedef __attribute__((ext_vector_type(8))) short short8;
typedef __attribute__((ext_vector_type(4))) float f32x4;

// ================= prep: conversions =================

__global__ void conv_h_kernel(const float* __restrict__ x, __hip_bfloat16* __restrict__ y) {
    int i = blockIdx.x * 256 + threadIdx.x;
    if (i < N_NODES * DIM) y[i] = __float2bfloat16(x[i]);
}

// W f32 [r][k][n] -> Wt bf16 [r][n][k], all 3 layers in one launch
__global__ void conv_wt3_kernel(const float* __restrict__ W1, const float* __restrict__ W2,
                                const float* __restrict__ W3,
                                __hip_bfloat16* __restrict__ Wt1,
                                __hip_bfloat16* __restrict__ Wt2,
                                __hip_bfloat16* __restrict__ Wt3) {
    const int n = N_RELS * DIM * DIM;
    int i = blockIdx.x * 256 + threadIdx.x;
    if (i >= 3 * n) return;
    int which = i / n, j = i - which * n;
    const float* W = (which == 0) ? W1 : (which == 1) ? W2 : W3;
    __hip_bfloat16* Wt = (which == 0) ? Wt1 : (which == 1) ? Wt2 : Wt3;
    int r = j >> 12, rest = j & 4095;
    int nn = rest >> 6, k = rest & 63;
    Wt[(size_t)r * 4096 + nn * 64 + k] = __float2bfloat16(W[(size_t)r * 4096 + k * 64 + nn]);
}

// ================= prep: rel-sort (block-stable counting sort) =================

__global__ __launch_bounds__(256) void hist2_kernel(const int* __restrict__ et,
                                                    int* __restrict__ blk_hist) {
    __shared__ int lh[N_RELS];
    int t = threadIdx.x, b = blockIdx.x;
    if (t < N_RELS) lh[t] = 0;
    __syncthreads();
    int lo = b * CHUNK;
    int hi = lo + CHUNK; if (hi > N_EDGES) hi = N_EDGES;
    for (int i = lo + t; i < hi; i += 256) atomicAdd(&lh[et[i]], 1);
    __syncthreads();
    if (t < N_RELS) blk_hist[b * N_RELS + t] = lh[t];
}

// wave-parallel per-relation scan over the 256 sort-blocks.
// wave r: blk_off[b][r] = exclusive prefix (local, no rel base); rel_tot[r] = total.
__global__ __launch_bounds__(256) void relwave_kernel(const int* __restrict__ blk_hist,
                                                      int* __restrict__ blk_off,
                                                      int* __restrict__ rel_tot) {
    int wave = blockIdx.x * 4 + (threadIdx.x >> 6);
    int lane = threadIdx.x & 63;
    if (wave >= N_RELS) return;
    int run = 0;
    for (int c = 0; c < SORT_BLOCKS; c += 64) {
        int b = c + lane;
        int v = blk_hist[b * N_RELS + wave];
        int x = v;
        #pragma unroll
        for (int off = 1; off < 64; off <<= 1) {
            int y = __shfl_up(x, off);
            if (lane >= off) x += y;
        }
        blk_off[b * N_RELS + wave] = run + x - v;  // exclusive
        run += __shfl(x, 63);
    }
    if (lane == 0) rel_tot[wave] = run;
}

// tiny: rel bases + tile bases from totals (LDS-staged serial over 65)
__global__ __launch_bounds__(128) void relbase_kernel(const int* __restrict__ rel_tot,
                                                      int* __restrict__ rel_ptr,
                                                      int* __restrict__ tile_base) {
    __shared__ int tot[N_RELS];
    int t = threadIdx.x;
    if (t < N_RELS) tot[t] = rel_tot[t];
    __syncthreads();
    if (t == 0) {
        int s = 0, tt = 0;
        for (int q = 0; q < N_RELS; ++q) {
            rel_ptr[q] = s; s += tot[q];
            tile_base[q] = tt; tt += (tot[q] + 15) >> 4;
        }
        rel_ptr[N_RELS] = N_EDGES;
        tile_base[N_RELS] = tt;
    }
}

// scatter: cur = local blk_off + rel base (rel_ptr)
__global__ __launch_bounds__(256) void scatter2_kernel(
    const int* __restrict__ et, const int* __restrict__ src,
    const int* __restrict__ dst, const int* __restrict__ blk_off,
    const int* __restrict__ rel_ptr,
    int* __restrict__ src_s, int* __restrict__ dst_s) {
    __shared__ int cur[N_RELS];
    int t = threadIdx.x, b = blockIdx.x;
    if (t < N_RELS) cur[t] = blk_off[b * N_RELS + t] + rel_ptr[t];
    __syncthreads();
    int lo = b * CHUNK;
    int hi = lo + CHUNK; if (hi > N_EDGES) hi = N_EDGES;
    for (int i = lo + t; i < hi; i += 256) {
        int r = et[i];
        int p = atomicAdd(&cur[r], 1);
        src_s[p] = src[i];
        dst_s[p] = dst[i];
    }
}

// ================= prep: dst CSR =================

__global__ void histdst_kernel(const int* __restrict__ dst, int* __restrict__ cnt_d) {
    int i = blockIdx.x * 256 + threadIdx.x;
    if (i < N_EDGES) atomicAdd(&cnt_d[dst[i]], 1);
}

__global__ __launch_bounds__(SCAN_BLK) void scanblk_kernel(const int* __restrict__ cnt,
                                                           int* __restrict__ outv,
                                                           int* __restrict__ blk_tot) {
    __shared__ int tmp[SCAN_BLK];
    int t = threadIdx.x;
    int i = blockIdx.x * SCAN_BLK + t;
    int v = (i < N_NODES) ? cnt[i] : 0;
    tmp[t] = v;
    __syncthreads();
    for (int off = 1; off < SCAN_BLK; off <<= 1) {
        int add = (t >= off) ? tmp[t - off] : 0;
        __syncthreads();
        tmp[t] += add;
        __syncthreads();
    }
    if (i < N_NODES) outv[i] = tmp[t] - v;  // exclusive
    if (t == SCAN_BLK - 1) blk_tot[blockIdx.x] = tmp[t];
}

__global__ void scantop_kernel(int* __restrict__ blk_tot, int* __restrict__ blk_base) {
    if (threadIdx.x == 0 && blockIdx.x == 0) {
        int run = 0;
        for (int b = 0; b < NSCAN_BLKS; ++b) { blk_base[b] = run; run += blk_tot[b]; }
    }
}

__global__ __launch_bounds__(SCAN_BLK) void scanadd_kernel(int* __restrict__ outv,
                                                           const int* __restrict__ blk_base) {
    int i = blockIdx.x * SCAN_BLK + threadIdx.x;
    if (i < N_NODES) outv[i] += blk_base[blockIdx.x];
}

// rank each rel-sorted edge within its dst bin -> dst-sorted slot
__global__ void dpos_kernel(const int* __restrict__ dst_s, int* __restrict__ cursor,
                            int* __restrict__ dpos) {
    int i = blockIdx.x * 256 + threadIdx.x;
    if (i < N_EDGES) dpos[i] = atomicAdd(&cursor[dst_s[i]], 1);
}

// ================= prep: graph segments (graph_ids sorted) =================

__global__ void histgid_kernel(const int* __restrict__ gid, int* __restrict__ cnt_g) {
    int i = blockIdx.x * 256 + threadIdx.x;
    if (i < N_NODES) atomicAdd(&cnt_g[gid[i]], 1);
}

__global__ __launch_bounds__(512) void scangid_kernel(const int* __restrict__ cnt_g,
                                                      int* __restrict__ g_ptr) {
    __shared__ int tmp[512];
    int t = threadIdx.x;
    int v = (t < N_GRAPHS) ? cnt_g[t] : 0;
    tmp[t] = v;
    __syncthreads();
    for (int off = 1; off < 512; off <<= 1) {
        int add = (t >= off) ? tmp[t - off] : 0;
        __syncthreads();
        tmp[t] += add;
        __syncthreads();
    }
    if (t < N_GRAPHS) g_ptr[t] = tmp[t] - v;
}

// ================= phase 1: MFMA message kernel =================
// Rel-sorted edges split into 16-edge tiles (tiles never cross relations;
// tile->rel via tile_base). 4096 waves grid-stride contiguous tile chunks:
// W[r] loaded once per relation-chunk into 8 short8 B-frags (32 VGPRs,
// register-resident). Per tile: gather 16 bf16 h rows -> LDS -> A-frags ->
// 8 MFMA -> C transposed through LDS -> coalesced 128B bf16 row stores into
// dst-sorted slots (dpos). No atomics.

__global__ __launch_bounds__(256) void msg_mfma_kernel(
    const __hip_bfloat16* __restrict__ hb, const __hip_bfloat16* __restrict__ Wt,
    const int* __restrict__ rel_ptr, const int* __restrict__ tile_base,
    const int* __restrict__ src_s, const int* __restrict__ dpos,
    __hip_bfloat16* __restrict__ msg) {
    __shared__ __align__(16) unsigned short stA[4][16 * 72];  // bf16 A stage, +8 pad
    __shared__ __align__(16) float stC[4][16 * 68];           // f32 C stage, +4 pad

    int t = threadIdx.x;
    int w = t >> 6, lane = t & 63;
    int quad = lane >> 4, m16 = lane & 15;
    int wave = blockIdx.x * 4 + w;

    int ntiles = tile_base[N_RELS];
    int tpw = (ntiles + NWAVES - 1) / NWAVES;
    int T = wave * tpw;
    int T1 = T + tpw; if (T1 > ntiles) T1 = ntiles;
    if (T >= T1) return;

    unsigned short* sa = &stA[w][0];
    float* sc = &stC[w][0];

    int r = 0;
    while (T >= tile_base[r + 1]) ++r;

    while (T < T1) {
        int chunk_end = tile_base[r + 1]; if (chunk_end > T1) chunk_end = T1;
        int seg_end = rel_ptr[r + 1];

        // B-frags: lane holds B[k=kt*32+quad*8+j][n=nt*16+m16] from Wt[r][n][k]
        const __hip_bfloat16* Wr = Wt + (size_t)r * (DIM * DIM);
        short8 bf00 = *(const short8*)(Wr + (0 * 16 + m16) * DIM + 0 * 32 + quad * 8);
        short8 bf01 = *(const short8*)(Wr + (1 * 16 + m16) * DIM + 0 * 32 + quad * 8);
        short8 bf02 = *(const short8*)(Wr + (2 * 16 + m16) * DIM + 0 * 32 + quad * 8);
        short8 bf03 = *(const short8*)(Wr + (3 * 16 + m16) * DIM + 0 * 32 + quad * 8);
        short8 bf10 = *(const short8*)(Wr + (0 * 16 + m16) * DIM + 1 * 32 + quad * 8);
        short8 bf11 = *(const short8*)(Wr + (1 * 16 + m16) * DIM + 1 * 32 + quad * 8);
        short8 bf12 = *(const short8*)(Wr + (2 * 16 + m16) * DIM + 1 * 32 + quad * 8);
        short8 bf13 = *(const short8*)(Wr + (3 * 16 + m16) * DIM + 1 * 32 + quad * 8);

        for (; T < chunk_end; ++T) {
            int e0 = rel_ptr[r] + (T - tile_base[r]) * 16;
            int rows = seg_end - e0; if (rows > 16) rows = 16;

            int sv = 0, dp = 0;
            if (lane < rows) { sv = src_s[e0 + lane]; dp = dpos[e0 + lane]; }

            // stage 16 rows (128 B each), 8 rows per pass
            #pragma unroll
            for (int half = 0; half < 2; ++half) {
                int row = (lane >> 3) + half * 8;
                int s = __shfl(sv, row);
                uint4 d; d.x = 0u; d.y = 0u; d.z = 0u; d.w = 0u;
                if (row < rows)
                    d = *(const uint4*)(hb + (size_t)s * DIM + (lane & 7) * 8);
                *(uint4*)&sa[row * 72 + (lane & 7) * 8] = d;
            }

            // A-frags: A[m16][kt*32 + quad*8 + j]
            short8 a0 = *(const short8*)&sa[m16 * 72 + quad * 8];
            short8 a1 = *(const short8*)&sa[m16 * 72 + 32 + quad * 8];

            f32x4 c0 = {0.f, 0.f, 0.f, 0.f}, c1 = c0, c2 = c0, c3 = c0;
            c0 = __builtin_amdgcn_mfma_f32_16x16x32_bf16(a0, bf00, c0, 0, 0, 0);
            c1 = __builtin_amdgcn_mfma_f32_16x16x32_bf16(a0, bf01, c1, 0, 0, 0);
            c2 = __builtin_amdgcn_mfma_f32_16x16x32_bf16(a0, bf02, c2, 0, 0, 0);
            c3 = __builtin_amdgcn_mfma_f32_16x16x32_bf16(a0, bf03, c3, 0, 0, 0);
            c0 = __builtin_amdgcn_mfma_f32_16x16x32_bf16(a1, bf10, c0, 0, 0, 0);
            c1 = __builtin_amdgcn_mfma_f32_16x16x32_bf16(a1, bf11, c1, 0, 0, 0);
            c2 = __builtin_amdgcn_mfma_f32_16x16x32_bf16(a1, bf12, c2, 0, 0, 0);
            c3 = __builtin_amdgcn_mfma_f32_16x16x32_bf16(a1, bf13, c3, 0, 0, 0);

            // C -> LDS (row = quad*4+reg, col = nt*16+m16)
            #pragma unroll
            for (int reg = 0; reg < 4; ++reg) {
                int rr = (quad * 4 + reg) * 68 + m16;
                sc[rr +  0] = c0[reg];
                sc[rr + 16] = c1[reg];
                sc[rr + 32] = c2[reg];
                sc[rr + 48] = c3[reg];
            }

            // read back rows, pack bf16, coalesced store (4 lanes / row)
            int orow = lane >> 2;
            if (orow < rows) {
                int c0i = (lane & 3) * 16;
                float vs[16];
                *(f32x4*)&vs[0]  = *(const f32x4*)&sc[orow * 68 + c0i + 0];
                *(f32x4*)&vs[4]  = *(const f32x4*)&sc[orow * 68 + c0i + 4];
                *(f32x4*)&vs[8]  = *(const f32x4*)&sc[orow * 68 + c0i + 8];
                *(f32x4*)&vs[12] = *(const f32x4*)&sc[orow * 68 + c0i + 12];
                unsigned short us[16];
                #pragma unroll
                for (int i = 0; i < 16; ++i)
                    us[i] = __hip_bfloat16_raw(__float2bfloat16(vs[i])).x;
                int dprow = __shfl(dp, orow);
                __hip_bfloat16* dst = msg + (size_t)dprow * DIM + c0i;
                *(uint4*)dst = *(const uint4*)&us[0];
                *(uint4*)(dst + 8) = *(const uint4*)&us[8];
            }
        }
        ++r;
        while (T < T1 && T >= tile_base[r + 1]) ++r;  // skip empty relations
    }
}

// ================= phase 2: pull-aggregate + bias + ReLU (bf16 out) =================

__global__ __launch_bounds__(256) void agg_kernel(
    const __hip_bfloat16* __restrict__ msg, const int* __restrict__ row_ptr,
    const int* __restrict__ cnt_d, const float* __restrict__ b,
    __hip_bfloat16* __restrict__ hout) {
    int wave = blockIdx.x * 4 + (threadIdx.x >> 6);
    int lane = threadIdx.x & 63;
    if (wave >= N_NODES) return;
    int j0 = row_ptr[wave];
    int n  = cnt_d[wave];
    float a0 = 0.f, a1 = 0.f, a2 = 0.f, a3 = 0.f;
    int j = 0;
    for (; j + 3 < n; j += 4) {
        a0 += __bfloat162float(msg[(size_t)(j0 + j + 0) * DIM + lane]);
        a1 += __bfloat162float(msg[(size_t)(j0 + j + 1) * DIM + lane]);
        a2 += __bfloat162float(msg[(size_t)(j0 + j + 2) * DIM + lane]);
        a3 += __bfloat162float(msg[(size_t)(j0 + j + 3) * DIM + lane]);
    }
    for (; j < n; ++j)
        a0 += __bfloat162float(msg[(size_t)(j0 + j) * DIM + lane]);
    float v = ((a0 + a1) + (a2 + a3)) + b[lane];
    hout[(size_t)wave * DIM + lane] = __float2bfloat16(v > 0.f ? v : 0.f);
}

// ================= graph sum-pool (segmented, bf16 h) =================

__global__ __launch_bounds__(256) void pool_seg_kernel(
    const __hip_bfloat16* __restrict__ h, const int* __restrict__ g_ptr,
    const int* __restrict__ cnt_g, float* __restrict__ g) {
    int wave = blockIdx.x * 4 + (threadIdx.x >> 6);
    int lane = threadIdx.x & 63;
    if (wave >= N_GRAPHS) return;
    int j0 = g_ptr[wave];
    int n  = cnt_g[wave];
    float a0 = 0.f, a1 = 0.f;
    int j = 0;
    for (; j + 1 < n; j += 2) {
        a0 += __bfloat162float(h[(size_t)(j0 + j) * DIM + lane]);
        a1 += __bfloat162float(h[(size_t)(j0 + j + 1) * DIM + lane]);
    }
    if (j < n) a0 += __bfloat162float(h[(size_t)(j0 + j) * DIM + lane]);
    g[(size_t)wave * DIM + lane] = a0 + a1;
}

// ================= fused FC x3 + prediction head =================

__global__ __launch_bounds__(256) void fc_kernel(
    const float* __restrict__ g,
    const float* __restrict__ W1, const float* __restrict__ b1,
    const float* __restrict__ W2, const float* __restrict__ b2,
    const float* __restrict__ W3, const float* __restrict__ b3,
    const float* __restrict__ pW, const float* __restrict__ pb,
    float* __restrict__ out) {
    int wave = blockIdx.x * 4 + (threadIdx.x >> 6);
    int lane = threadIdx.x & 63;
    if (wave >= N_GRAPHS) return;

    float v = g[(size_t)wave * DIM + lane];

    const float* Ws[3] = {W1, W2, W3};
    const float* bs[3] = {b1, b2, b3};
    for (int l = 0; l < 3; ++l) {
        float acc = bs[l][lane];
        const float* __restrict__ Wl = Ws[l];
        #pragma unroll
        for (int d = 0; d < DIM; ++d)
            acc += __shfl(v, d) * Wl[d * DIM + lane];
        v = acc > 0.f ? acc : 0.f;
    }

    float p0 = v * pW[lane * 2 + 0];
    float p1 = v * pW[lane * 2 + 1];
    #pragma unroll
    for (int off = 32; off > 0; off >>= 1) {
        p0 += __shfl_down(p0, off);
        p1 += __shfl_down(p1, off);
    }
    if (lane == 0) {
        out[wave * 2 + 0] = p0 + pb[0];
        out[wave * 2 + 1] = p1 + pb[1];
    }
}

// ================= launch =================

extern "C" void kernel_launch(void* const* d_in, const int* in_sizes, int n_in,
                              void* d_out, int out_size, void* d_ws, size_t ws_size,
                              hipStream_t stream) {
    const float* node_feats = (const float*)d_in[0];
    const int*   etypes     = (const int*)d_in[1];
    const int*   src        = (const int*)d_in[2];
    const int*   dst        = (const int*)d_in[3];
    const int*   graph_ids  = (const int*)d_in[4];
    const float* W1 = (const float*)d_in[5];
    const float* b1 = (const float*)d_in[6];
    const float* W2 = (const float*)d_in[7];
    const float* b2 = (const float*)d_in[8];
    const float* W3 = (const float*)d_in[9];
    const float* b3 = (const float*)d_in[10];
    const float* fcW1 = (const float*)d_in[11];
    const float* fcb1 = (const float*)d_in[12];
    const float* fcW2 = (const float*)d_in[13];
    const float* fcb2 = (const float*)d_in[14];
    const float* fcW3 = (const float*)d_in[15];
    const float* fcb3 = (const float*)d_in[16];
    const float* pW = (const float*)d_in[17];
    const float* pb = (const float*)d_in[18];
    float* out = (float*)d_out;

    // workspace carve-up (256B aligned)
    char* p = (char*)d_ws;
    auto alloc = [&](size_t bytes) -> void* {
        void* r = (void*)p;
        p += (bytes + 255) & ~(size_t)255;
        return r;
    };
    int* blk_hist  = (int*)alloc((size_t)SORT_BLOCKS * N_RELS * sizeof(int));
    int* blk_off   = (int*)alloc((size_t)SORT_BLOCKS * N_RELS * sizeof(int));
    int* rel_tot   = (int*)alloc(N_RELS * sizeof(int));
    int* rel_ptr   = (int*)alloc((N_RELS + 1) * sizeof(int));
    int* tile_base = (int*)alloc((N_RELS + 1) * sizeof(int));
    int* src_s     = (int*)alloc((size_t)N_EDGES * sizeof(int));
    int* dst_s     = (int*)alloc((size_t)N_EDGES * sizeof(int));
    int* dpos      = (int*)alloc((size_t)N_EDGES * sizeof(int));
    int* cnt_d     = (int*)alloc((size_t)N_NODES * sizeof(int));
    int* row_ptr   = (int*)alloc((size_t)N_NODES * sizeof(int));
    int* cursor_d  = (int*)alloc((size_t)N_NODES * sizeof(int));
    int* blk_tot   = (int*)alloc(NSCAN_BLKS * sizeof(int));
    int* blk_base  = (int*)alloc(NSCAN_BLKS * sizeof(int));
    int* cnt_g     = (int*)alloc(N_GRAPHS * sizeof(int));
    int* g_ptr     = (int*)alloc(N_GRAPHS * sizeof(int));
    float* g       = (float*)alloc((size_t)N_GRAPHS * DIM * sizeof(float));
    __hip_bfloat16* hb0 = (__hip_bfloat16*)alloc((size_t)N_NODES * DIM * sizeof(__hip_bfloat16));
    __hip_bfloat16* hb1 = (__hip_bfloat16*)alloc((size_t)N_NODES * DIM * sizeof(__hip_bfloat16));
    __hip_bfloat16* Wt1 = (__hip_bfloat16*)alloc((size_t)N_RELS * DIM * DIM * sizeof(__hip_bfloat16));
    __hip_bfloat16* Wt2 = (__hip_bfloat16*)alloc((size_t)N_RELS * DIM * DIM * sizeof(__hip_bfloat16));
    __hip_bfloat16* Wt3 = (__hip_bfloat16*)alloc((size_t)N_RELS * DIM * DIM * sizeof(__hip_bfloat16));
    __hip_bfloat16* msg = (__hip_bfloat16*)alloc((size_t)N_EDGES * DIM * sizeof(__hip_bfloat16));

    const int EBLK = (N_EDGES + 255) / 256;              // 3125
    const int HBLK = (N_NODES * DIM + 255) / 256;        // 12500
    const int W3BLK = (3 * N_RELS * DIM * DIM + 255) / 256;
    const int NBLK256 = (N_NODES + 255) / 256;           // 196
    const int AGG_BLOCKS = (N_NODES + 3) / 4;            // 12500

    // ---- prep: conversions ----
    conv_h_kernel<<<HBLK, 256, 0, stream>>>(node_feats, hb0);
    conv_wt3_kernel<<<W3BLK, 256, 0, stream>>>(W1, W2, W3, Wt1, Wt2, Wt3);

    // ---- prep: rel-sort ----
    hist2_kernel<<<SORT_BLOCKS, 256, 0, stream>>>(etypes, blk_hist);
    relwave_kernel<<<(N_RELS + 3) / 4, 256, 0, stream>>>(blk_hist, blk_off, rel_tot);
    relbase_kernel<<<1, 128, 0, stream>>>(rel_tot, rel_ptr, tile_base);
    scatter2_kernel<<<SORT_BLOCKS, 256, 0, stream>>>(etypes, src, dst, blk_off, rel_ptr,
                                                     src_s, dst_s);

    // ---- prep: dst CSR ----
    hipMemsetAsync(cnt_d, 0, (size_t)N_NODES * sizeof(int), stream);
    histdst_kernel<<<EBLK, 256, 0, stream>>>(dst, cnt_d);
    scanblk_kernel<<<NSCAN_BLKS, SCAN_BLK, 0, stream>>>(cnt_d, row_ptr, blk_tot);
    scantop_kernel<<<1, 64, 0, stream>>>(blk_tot, blk_base);
    scanadd_kernel<<<NSCAN_BLKS, SCAN_BLK, 0, stream>>>(row_ptr, blk_base);
    hipMemcpyAsync(cursor_d, row_ptr, (size_t)N_NODES * sizeof(int),
                   hipMemcpyDeviceToDevice, stream);
    dpos_kernel<<<EBLK, 256, 0, stream>>>(dst_s, cursor_d, dpos);

    // ---- prep: graph segments ----
    hipMemsetAsync(cnt_g, 0, N_GRAPHS * sizeof(int), stream);
    histgid_kernel<<<NBLK256, 256, 0, stream>>>(graph_ids, cnt_g);
    scangid_kernel<<<1, 512, 0, stream>>>(cnt_g, g_ptr);

    // ---- 3 RGCN layers ----
    msg_mfma_kernel<<<MSG_BLOCKS, 256, 0, stream>>>(hb0, Wt1, rel_ptr, tile_base,
                                                    src_s, dpos, msg);
    agg_kernel<<<AGG_BLOCKS, 256, 0, stream>>>(msg, row_ptr, cnt_d, b1, hb1);

    msg_mfma_kernel<<<MSG_BLOCKS, 256, 0, stream>>>(hb1, Wt2, rel_ptr, tile_base,
                                                    src_s, dpos, msg);
    agg_kernel<<<AGG_BLOCKS, 256, 0, stream>>>(msg, row_ptr, cnt_d, b2, hb0);

    msg_mfma_kernel<<<MSG_BLOCKS, 256, 0, stream>>>(hb0, Wt3, rel_ptr, tile_base,
                                                    src_s, dpos, msg);
    agg_kernel<<<AGG_BLOCKS, 256, 0, stream>>>(msg, row_ptr, cnt_d, b3, hb1);

    // ---- pool + FC head ----
    pool_seg_kernel<<<(N_GRAPHS + 3) / 4, 256, 0, stream>>>(hb1, g_ptr, cnt_g, g);
    fc_kernel<<<(N_GRAPHS + 3) / 4, 256, 0, stream>>>(g, fcW1, fcb1, fcW2, fcb2,
                                                      fcW3, fcb3, pW, pb, out);
}

// Round 7
// 421.430 us; speedup vs baseline: 4.3113x; 1.0725x over previous
//
#include <hip/hip_runtime.h>
#include <hip/hip_bf16.h>

#define N_NODES 50000
#define N_EDGES 800000
#define N_RELS 65
#define DIM 64
#define N_GRAPHS 512

#define SORT_BLOCKS 256
#define CHUNK ((N_EDGES + SORT_BLOCKS - 1) / SORT_BLOCKS)  // 3125

#define SCAN_BLK 512
#define NSCAN_BLKS ((N_NODES + SCAN_BLK - 1) / SCAN_BLK)   // 98

#define MSG_BLOCKS 1024
#define NWAVES (MSG_BLOCKS * 4)

typedef __attribute__((ext_vector_type(8))) short short8;
typedef __attribute__((ext_vector_type(4))) float f32x4;

// ================= prep: conversions (+ zero the histogram buffers) =================

__global__ void conv_h_zero_kernel(const float* __restrict__ x, __hip_bfloat16* __restrict__ y,
                                   int* __restrict__ cnt_d, int* __restrict__ cnt_g) {
    int i = blockIdx.x * 256 + threadIdx.x;
    if (i < N_NODES * DIM) y[i] = __float2bfloat16(x[i]);
    if (i < N_NODES) cnt_d[i] = 0;
    if (i < N_GRAPHS) cnt_g[i] = 0;
}

// W f32 [r][k][n] -> Wt bf16 [r][n][k], all 3 layers in one launch
__global__ void conv_wt3_kernel(const float* __restrict__ W1, const float* __restrict__ W2,
                                const float* __restrict__ W3,
                                __hip_bfloat16* __restrict__ Wt1,
                                __hip_bfloat16* __restrict__ Wt2,
                                __hip_bfloat16* __restrict__ Wt3) {
    const int n = N_RELS * DIM * DIM;
    int i = blockIdx.x * 256 + threadIdx.x;
    if (i >= 3 * n) return;
    int which = i / n, j = i - which * n;
    const float* W = (which == 0) ? W1 : (which == 1) ? W2 : W3;
    __hip_bfloat16* Wt = (which == 0) ? Wt1 : (which == 1) ? Wt2 : Wt3;
    int r = j >> 12, rest = j & 4095;
    int nn = rest >> 6, k = rest & 63;
    Wt[(size_t)r * 4096 + nn * 64 + k] = __float2bfloat16(W[(size_t)r * 4096 + k * 64 + nn]);
}

// ================= prep: rel-sort (block-stable counting sort) =================

__global__ __launch_bounds__(256) void hist2_kernel(const int* __restrict__ et,
                                                    int* __restrict__ blk_hist) {
    __shared__ int lh[N_RELS];
    int t = threadIdx.x, b = blockIdx.x;
    if (t < N_RELS) lh[t] = 0;
    __syncthreads();
    int lo = b * CHUNK;
    int hi = lo + CHUNK; if (hi > N_EDGES) hi = N_EDGES;
    for (int i = lo + t; i < hi; i += 256) atomicAdd(&lh[et[i]], 1);
    __syncthreads();
    if (t < N_RELS) blk_hist[b * N_RELS + t] = lh[t];
}

// wave-parallel per-relation scan over the 256 sort-blocks
__global__ __launch_bounds__(256) void relwave_kernel(const int* __restrict__ blk_hist,
                                                      int* __restrict__ blk_off,
                                                      int* __restrict__ rel_tot) {
    int wave = blockIdx.x * 4 + (threadIdx.x >> 6);
    int lane = threadIdx.x & 63;
    if (wave >= N_RELS) return;
    int run = 0;
    for (int c = 0; c < SORT_BLOCKS; c += 64) {
        int b = c + lane;
        int v = blk_hist[b * N_RELS + wave];
        int x = v;
        #pragma unroll
        for (int off = 1; off < 64; off <<= 1) {
            int y = __shfl_up(x, off);
            if (lane >= off) x += y;
        }
        blk_off[b * N_RELS + wave] = run + x - v;  // exclusive
        run += __shfl(x, 63);
    }
    if (lane == 0) rel_tot[wave] = run;
}

// tiny: rel bases + tile bases from totals
__global__ __launch_bounds__(128) void relbase_kernel(const int* __restrict__ rel_tot,
                                                      int* __restrict__ rel_ptr,
                                                      int* __restrict__ tile_base) {
    __shared__ int tot[N_RELS];
    int t = threadIdx.x;
    if (t < N_RELS) tot[t] = rel_tot[t];
    __syncthreads();
    if (t == 0) {
        int s = 0, tt = 0;
        for (int q = 0; q < N_RELS; ++q) {
            rel_ptr[q] = s; s += tot[q];
            tile_base[q] = tt; tt += (tot[q] + 15) >> 4;
        }
        rel_ptr[N_RELS] = N_EDGES;
        tile_base[N_RELS] = tt;
    }
}

__global__ __launch_bounds__(256) void scatter2_kernel(
    const int* __restrict__ et, const int* __restrict__ src,
    const int* __restrict__ dst, const int* __restrict__ blk_off,
    const int* __restrict__ rel_ptr,
    int* __restrict__ src_s, int* __restrict__ dst_s) {
    __shared__ int cur[N_RELS];
    int t = threadIdx.x, b = blockIdx.x;
    if (t < N_RELS) cur[t] = blk_off[b * N_RELS + t] + rel_ptr[t];
    __syncthreads();
    int lo = b * CHUNK;
    int hi = lo + CHUNK; if (hi > N_EDGES) hi = N_EDGES;
    for (int i = lo + t; i < hi; i += 256) {
        int r = et[i];
        int p = atomicAdd(&cur[r], 1);
        src_s[p] = src[i];
        dst_s[p] = dst[i];
    }
}

// ================= prep: dst CSR =================

__global__ void histdst_kernel(const int* __restrict__ dst, int* __restrict__ cnt_d) {
    int i = blockIdx.x * 256 + threadIdx.x;
    if (i < N_EDGES) atomicAdd(&cnt_d[dst[i]], 1);
}

__global__ __launch_bounds__(SCAN_BLK) void scanblk_kernel(const int* __restrict__ cnt,
                                                           int* __restrict__ outv,
                                                           int* __restrict__ blk_tot) {
    __shared__ int tmp[SCAN_BLK];
    int t = threadIdx.x;
    int i = blockIdx.x * SCAN_BLK + t;
    int v = (i < N_NODES) ? cnt[i] : 0;
    tmp[t] = v;
    __syncthreads();
    for (int off = 1; off < SCAN_BLK; off <<= 1) {
        int add = (t >= off) ? tmp[t - off] : 0;
        __syncthreads();
        tmp[t] += add;
        __syncthreads();
    }
    if (i < N_NODES) outv[i] = tmp[t] - v;  // exclusive
    if (t == SCAN_BLK - 1) blk_tot[blockIdx.x] = tmp[t];
}

__global__ void scantop_kernel(int* __restrict__ blk_tot, int* __restrict__ blk_base) {
    if (threadIdx.x == 0 && blockIdx.x == 0) {
        int run = 0;
        for (int b = 0; b < NSCAN_BLKS; ++b) { blk_base[b] = run; run += blk_tot[b]; }
    }
}

// adds block bases AND seeds the dpos cursor (folds the old memcpy)
__global__ __launch_bounds__(SCAN_BLK) void scanadd_kernel(int* __restrict__ outv,
                                                           int* __restrict__ cursor,
                                                           const int* __restrict__ blk_base) {
    int i = blockIdx.x * SCAN_BLK + threadIdx.x;
    if (i < N_NODES) {
        int v = outv[i] + blk_base[blockIdx.x];
        outv[i] = v;
        cursor[i] = v;
    }
}

__global__ void dpos_kernel(const int* __restrict__ dst_s, int* __restrict__ cursor,
                            int* __restrict__ dpos) {
    int i = blockIdx.x * 256 + threadIdx.x;
    if (i < N_EDGES) dpos[i] = atomicAdd(&cursor[dst_s[i]], 1);
}

// ================= prep: graph segments (graph_ids sorted) =================

__global__ void histgid_kernel(const int* __restrict__ gid, int* __restrict__ cnt_g) {
    int i = blockIdx.x * 256 + threadIdx.x;
    if (i < N_NODES) atomicAdd(&cnt_g[gid[i]], 1);
}

__global__ __launch_bounds__(512) void scangid_kernel(const int* __restrict__ cnt_g,
                                                      int* __restrict__ g_ptr) {
    __shared__ int tmp[512];
    int t = threadIdx.x;
    int v = (t < N_GRAPHS) ? cnt_g[t] : 0;
    tmp[t] = v;
    __syncthreads();
    for (int off = 1; off < 512; off <<= 1) {
        int add = (t >= off) ? tmp[t - off] : 0;
        __syncthreads();
        tmp[t] += add;
        __syncthreads();
    }
    if (t < N_GRAPHS) g_ptr[t] = tmp[t] - v;
}

// ================= phase 1: MFMA message kernel (register-prefetch pipeline) =================

__global__ __launch_bounds__(256) void msg_mfma_kernel(
    const __hip_bfloat16* __restrict__ hb, const __hip_bfloat16* __restrict__ Wt,
    const int* __restrict__ rel_ptr, const int* __restrict__ tile_base,
    const int* __restrict__ src_s, const int* __restrict__ dpos,
    __hip_bfloat16* __restrict__ msg) {
    __shared__ __align__(16) unsigned short stA[4][16 * 72];  // bf16 A stage, +8 pad
    __shared__ __align__(16) float stC[4][16 * 68];           // f32 C stage, +4 pad

    int t = threadIdx.x;
    int w = t >> 6, lane = t & 63;
    int quad = lane >> 4, m16 = lane & 15;
    int wave = blockIdx.x * 4 + w;

    int ntiles = tile_base[N_RELS];
    int tpw = (ntiles + NWAVES - 1) / NWAVES;
    int T = wave * tpw;
    int T1 = T + tpw; if (T1 > ntiles) T1 = ntiles;
    if (T >= T1) return;

    unsigned short* sa = &stA[w][0];
    float* sc = &stC[w][0];

    int r = 0;
    while (T >= tile_base[r + 1]) ++r;

    while (T < T1) {
        int chunk_end = tile_base[r + 1]; if (chunk_end > T1) chunk_end = T1;
        int e_base = rel_ptr[r], t_base = tile_base[r];
        int seg_end = rel_ptr[r + 1];

        // B-frags: lane holds B[k=kt*32+quad*8+j][n=nt*16+m16] from Wt[r][n][k]
        const __hip_bfloat16* Wr = Wt + (size_t)r * (DIM * DIM);
        short8 bf00 = *(const short8*)(Wr + (0 * 16 + m16) * DIM + 0 * 32 + quad * 8);
        short8 bf01 = *(const short8*)(Wr + (1 * 16 + m16) * DIM + 0 * 32 + quad * 8);
        short8 bf02 = *(const short8*)(Wr + (2 * 16 + m16) * DIM + 0 * 32 + quad * 8);
        short8 bf03 = *(const short8*)(Wr + (3 * 16 + m16) * DIM + 0 * 32 + quad * 8);
        short8 bf10 = *(const short8*)(Wr + (0 * 16 + m16) * DIM + 1 * 32 + quad * 8);
        short8 bf11 = *(const short8*)(Wr + (1 * 16 + m16) * DIM + 1 * 32 + quad * 8);
        short8 bf12 = *(const short8*)(Wr + (2 * 16 + m16) * DIM + 1 * 32 + quad * 8);
        short8 bf13 = *(const short8*)(Wr + (3 * 16 + m16) * DIM + 1 * 32 + quad * 8);

        // ---- software pipeline over tiles of this relation chunk ----
        // idx loads (clamped, unconditional); gather into registers.
        auto eidx = [&](int TT) {
            int i = e_base + (TT - t_base) * 16 + lane;
            return i < N_EDGES ? i : N_EDGES - 1;
        };

        int sv_c, dp_c, sv_n = 0, dp_n = 0, sv_nn = 0, dp_nn = 0;
        uint4 g0_c, g1_c;
        {
            int i0 = eidx(T);
            sv_c = src_s[i0]; dp_c = dpos[i0];
            int r0 = lane >> 3;
            int s0 = __shfl(sv_c, r0);
            int s1 = __shfl(sv_c, r0 + 8);
            g0_c = *(const uint4*)(hb + (size_t)s0 * DIM + (lane & 7) * 8);
            g1_c = *(const uint4*)(hb + (size_t)s1 * DIM + (lane & 7) * 8);
            if (T + 1 < chunk_end) {
                int i1 = eidx(T + 1);
                sv_n = src_s[i1]; dp_n = dpos[i1];
            }
        }

        for (; T < chunk_end; ++T) {
            int e0 = e_base + (T - t_base) * 16;
            int rows = seg_end - e0; if (rows > 16) rows = 16;

            // stage current tile (regs -> LDS)
            int r0 = lane >> 3;
            *(uint4*)&sa[r0 * 72 + (lane & 7) * 8] = g0_c;
            *(uint4*)&sa[(r0 + 8) * 72 + (lane & 7) * 8] = g1_c;

            // prefetch: gather T+1 (sv_n loaded last iter), idx-load T+2
            uint4 g0_n, g1_n;
            bool hasN = (T + 1 < chunk_end);
            if (hasN) {
                int s0 = __shfl(sv_n, r0);
                int s1 = __shfl(sv_n, r0 + 8);
                g0_n = *(const uint4*)(hb + (size_t)s0 * DIM + (lane & 7) * 8);
                g1_n = *(const uint4*)(hb + (size_t)s1 * DIM + (lane & 7) * 8);
            }
            if (T + 2 < chunk_end) {
                int i2 = eidx(T + 2);
                sv_nn = src_s[i2]; dp_nn = dpos[i2];
            }

            // A-frags: A[m16][kt*32 + quad*8 + j]
            short8 a0 = *(const short8*)&sa[m16 * 72 + quad * 8];
            short8 a1 = *(const short8*)&sa[m16 * 72 + 32 + quad * 8];

            f32x4 c0 = {0.f, 0.f, 0.f, 0.f}, c1 = c0, c2 = c0, c3 = c0;
            c0 = __builtin_amdgcn_mfma_f32_16x16x32_bf16(a0, bf00, c0, 0, 0, 0);
            c1 = __builtin_amdgcn_mfma_f32_16x16x32_bf16(a0, bf01, c1, 0, 0, 0);
            c2 = __builtin_amdgcn_mfma_f32_16x16x32_bf16(a0, bf02, c2, 0, 0, 0);
            c3 = __builtin_amdgcn_mfma_f32_16x16x32_bf16(a0, bf03, c3, 0, 0, 0);
            c0 = __builtin_amdgcn_mfma_f32_16x16x32_bf16(a1, bf10, c0, 0, 0, 0);
            c1 = __builtin_amdgcn_mfma_f32_16x16x32_bf16(a1, bf11, c1, 0, 0, 0);
            c2 = __builtin_amdgcn_mfma_f32_16x16x32_bf16(a1, bf12, c2, 0, 0, 0);
            c3 = __builtin_amdgcn_mfma_f32_16x16x32_bf16(a1, bf13, c3, 0, 0, 0);

            // C -> LDS (row = quad*4+reg, col = nt*16+m16)
            #pragma unroll
            for (int reg = 0; reg < 4; ++reg) {
                int rr = (quad * 4 + reg) * 68 + m16;
                sc[rr +  0] = c0[reg];
                sc[rr + 16] = c1[reg];
                sc[rr + 32] = c2[reg];
                sc[rr + 48] = c3[reg];
            }

            // read back rows, pack bf16, coalesced store (4 lanes / row)
            int orow = lane >> 2;
            if (orow < rows) {
                int c0i = (lane & 3) * 16;
                float vs[16];
                *(f32x4*)&vs[0]  = *(const f32x4*)&sc[orow * 68 + c0i + 0];
                *(f32x4*)&vs[4]  = *(const f32x4*)&sc[orow * 68 + c0i + 4];
                *(f32x4*)&vs[8]  = *(const f32x4*)&sc[orow * 68 + c0i + 8];
                *(f32x4*)&vs[12] = *(const f32x4*)&sc[orow * 68 + c0i + 12];
                unsigned short us[16];
                #pragma unroll
                for (int i = 0; i < 16; ++i)
                    us[i] = __hip_bfloat16_raw(__float2bfloat16(vs[i])).x;
                int dprow = __shfl(dp_c, orow);
                __hip_bfloat16* dst = msg + (size_t)dprow * DIM + c0i;
                *(uint4*)dst = *(const uint4*)&us[0];
                *(uint4*)(dst + 8) = *(const uint4*)&us[8];
            }

            // rotate pipeline registers
            if (hasN) { g0_c = g0_n; g1_c = g1_n; }
            sv_c = sv_n; dp_c = dp_n;
            sv_n = sv_nn; dp_n = dp_nn;
        }
        ++r;
        while (T < T1 && T >= tile_base[r + 1]) ++r;  // skip empty relations
    }
}

// ================= phase 2: vectorized pull-aggregate + bias + ReLU =================
// Lane l loads uint4 = 8 bf16 of row jj+(l>>3), dims (l&7)*8..+8  (1 KB/wave/instr),
// then 24 shfl_xor reduce the 8 row-groups; lanes 0..7 store 16 B each.

__global__ __launch_bounds__(256) void agg_kernel(
    const __hip_bfloat16* __restrict__ msg, const int* __restrict__ row_ptr,
    const int* __restrict__ cnt_d, const float* __restrict__ b,
    __hip_bfloat16* __restrict__ hout) {
    int wave = blockIdx.x * 4 + (threadIdx.x >> 6);
    int lane = threadIdx.x & 63;
    if (wave >= N_NODES) return;
    int j0 = row_ptr[wave];
    int n  = cnt_d[wave];
    int rgrp = lane >> 3, dgrp = lane & 7;

    float a[8] = {0.f, 0.f, 0.f, 0.f, 0.f, 0.f, 0.f, 0.f};
    for (int jj = 0; jj < n; jj += 8) {
        int row = jj + rgrp;
        if (row < n) {
            uint4 d = *(const uint4*)(msg + (size_t)(j0 + row) * DIM + dgrp * 8);
            a[0] += __uint_as_float(d.x << 16);
            a[1] += __uint_as_float(d.x & 0xffff0000u);
            a[2] += __uint_as_float(d.y << 16);
            a[3] += __uint_as_float(d.y & 0xffff0000u);
            a[4] += __uint_as_float(d.z << 16);
            a[5] += __uint_as_float(d.z & 0xffff0000u);
            a[6] += __uint_as_float(d.w << 16);
            a[7] += __uint_as_float(d.w & 0xffff0000u);
        }
    }
    #pragma unroll
    for (int i = 0; i < 8; ++i) {
        a[i] += __shfl_xor(a[i], 8);
        a[i] += __shfl_xor(a[i], 16);
        a[i] += __shfl_xor(a[i], 32);
    }
    if (rgrp == 0) {
        unsigned short us[8];
        #pragma unroll
        for (int i = 0; i < 8; ++i) {
            float v = a[i] + b[dgrp * 8 + i];
            us[i] = __hip_bfloat16_raw(__float2bfloat16(v > 0.f ? v : 0.f)).x;
        }
        *(uint4*)(hout + (size_t)wave * DIM + dgrp * 8) = *(const uint4*)us;
    }
}

// ================= fused pool + FC x3 + prediction head =================
// One wave per graph. Pool uses the same 8x8 vectorized reduction; FC1 consumes
// the pooled 8x8 register layout directly via shfl(a[o], q) (g[q*8+o] lives in lane q).

__global__ __launch_bounds__(256) void poolfc_kernel(
    const __hip_bfloat16* __restrict__ h, const int* __restrict__ g_ptr,
    const int* __restrict__ cnt_g,
    const float* __restrict__ W1, const float* __restrict__ b1,
    const float* __restrict__ W2, const float* __restrict__ b2,
    const float* __restrict__ W3, const float* __restrict__ b3,
    const float* __restrict__ pW, const float* __restrict__ pb,
    float* __restrict__ out) {
    int wave = blockIdx.x * 4 + (threadIdx.x >> 6);
    int lane = threadIdx.x & 63;
    if (wave >= N_GRAPHS) return;
    int j0 = g_ptr[wave];
    int n  = cnt_g[wave];
    int rgrp = lane >> 3, dgrp = lane & 7;

    float a[8] = {0.f, 0.f, 0.f, 0.f, 0.f, 0.f, 0.f, 0.f};
    for (int jj = 0; jj < n; jj += 8) {
        int row = jj + rgrp;
        if (row < n) {
            uint4 d = *(const uint4*)(h + (size_t)(j0 + row) * DIM + dgrp * 8);
            a[0] += __uint_as_float(d.x << 16);
            a[1] += __uint_as_float(d.x & 0xffff0000u);
            a[2] += __uint_as_float(d.y << 16);
            a[3] += __uint_as_float(d.y & 0xffff0000u);
            a[4] += __uint_as_float(d.z << 16);
            a[5] += __uint_as_float(d.z & 0xffff0000u);
            a[6] += __uint_as_float(d.w << 16);
            a[7] += __uint_as_float(d.w & 0xffff0000u);
        }
    }
    #pragma unroll
    for (int i = 0; i < 8; ++i) {
        a[i] += __shfl_xor(a[i], 8);
        a[i] += __shfl_xor(a[i], 16);
        a[i] += __shfl_xor(a[i], 32);
    }
    // FC1 straight from the 8x8 layout: g[q*8+o] is a[o] on lane q
    float v;
    {
        float acc = b1[lane];
        #pragma unroll
        for (int o = 0; o < 8; ++o)
            #pragma unroll
            for (int q = 0; q < 8; ++q)
                acc += __shfl(a[o], q) * W1[(q * 8 + o) * DIM + lane];
        v = acc > 0.f ? acc : 0.f;
    }
    // FC2, FC3 with lane=dim layout
    {
        float acc = b2[lane];
        #pragma unroll
        for (int d = 0; d < DIM; ++d)
            acc += __shfl(v, d) * W2[d * DIM + lane];
        v = acc > 0.f ? acc : 0.f;
    }
    {
        float acc = b3[lane];
        #pragma unroll
        for (int d = 0; d < DIM; ++d)
            acc += __shfl(v, d) * W3[d * DIM + lane];
        v = acc > 0.f ? acc : 0.f;
    }
    float p0 = v * pW[lane * 2 + 0];
    float p1 = v * pW[lane * 2 + 1];
    #pragma unroll
    for (int off = 32; off > 0; off >>= 1) {
        p0 += __shfl_down(p0, off);
        p1 += __shfl_down(p1, off);
    }
    if (lane == 0) {
        out[wave * 2 + 0] = p0 + pb[0];
        out[wave * 2 + 1] = p1 + pb[1];
    }
}

// ================= launch =================

extern "C" void kernel_launch(void* const* d_in, const int* in_sizes, int n_in,
                              void* d_out, int out_size, void* d_ws, size_t ws_size,
                              hipStream_t stream) {
    const float* node_feats = (const float*)d_in[0];
    const int*   etypes     = (const int*)d_in[1];
    const int*   src        = (const int*)d_in[2];
    const int*   dst        = (const int*)d_in[3];
    const int*   graph_ids  = (const int*)d_in[4];
    const float* W1 = (const float*)d_in[5];
    const float* b1 = (const float*)d_in[6];
    const float* W2 = (const float*)d_in[7];
    const float* b2 = (const float*)d_in[8];
    const float* W3 = (const float*)d_in[9];
    const float* b3 = (const float*)d_in[10];
    const float* fcW1 = (const float*)d_in[11];
    const float* fcb1 = (const float*)d_in[12];
    const float* fcW2 = (const float*)d_in[13];
    const float* fcb2 = (const float*)d_in[14];
    const float* fcW3 = (const float*)d_in[15];
    const float* fcb3 = (const float*)d_in[16];
    const float* pW = (const float*)d_in[17];
    const float* pb = (const float*)d_in[18];
    float* out = (float*)d_out;

    // workspace carve-up (256B aligned)
    char* p = (char*)d_ws;
    auto alloc = [&](size_t bytes) -> void* {
        void* r = (void*)p;
        p += (bytes + 255) & ~(size_t)255;
        return r;
    };
    int* blk_hist  = (int*)alloc((size_t)SORT_BLOCKS * N_RELS * sizeof(int));
    int* blk_off   = (int*)alloc((size_t)SORT_BLOCKS * N_RELS * sizeof(int));
    int* rel_tot   = (int*)alloc(N_RELS * sizeof(int));
    int* rel_ptr   = (int*)alloc((N_RELS + 1) * sizeof(int));
    int* tile_base = (int*)alloc((N_RELS + 1) * sizeof(int));
    int* src_s     = (int*)alloc((size_t)N_EDGES * sizeof(int));
    int* dst_s     = (int*)alloc((size_t)N_EDGES * sizeof(int));
    int* dpos      = (int*)alloc((size_t)N_EDGES * sizeof(int));
    int* cnt_d     = (int*)alloc((size_t)N_NODES * sizeof(int));
    int* row_ptr   = (int*)alloc((size_t)N_NODES * sizeof(int));
    int* cursor_d  = (int*)alloc((size_t)N_NODES * sizeof(int));
    int* blk_tot   = (int*)alloc(NSCAN_BLKS * sizeof(int));
    int* blk_base  = (int*)alloc(NSCAN_BLKS * sizeof(int));
    int* cnt_g     = (int*)alloc(N_GRAPHS * sizeof(int));
    int* g_ptr     = (int*)alloc(N_GRAPHS * sizeof(int));
    __hip_bfloat16* hb0 = (__hip_bfloat16*)alloc((size_t)N_NODES * DIM * sizeof(__hip_bfloat16));
    __hip_bfloat16* hb1 = (__hip_bfloat16*)alloc((size_t)N_NODES * DIM * sizeof(__hip_bfloat16));
    __hip_bfloat16* Wt1 = (__hip_bfloat16*)alloc((size_t)N_RELS * DIM * DIM * sizeof(__hip_bfloat16));
    __hip_bfloat16* Wt2 = (__hip_bfloat16*)alloc((size_t)N_RELS * DIM * DIM * sizeof(__hip_bfloat16));
    __hip_bfloat16* Wt3 = (__hip_bfloat16*)alloc((size_t)N_RELS * DIM * DIM * sizeof(__hip_bfloat16));
    __hip_bfloat16* msg = (__hip_bfloat16*)alloc((size_t)N_EDGES * DIM * sizeof(__hip_bfloat16));

    const int EBLK = (N_EDGES + 255) / 256;              // 3125
    const int HBLK = (N_NODES * DIM + 255) / 256;        // 12500
    const int W3BLK = (3 * N_RELS * DIM * DIM + 255) / 256;
    const int NBLK256 = (N_NODES + 255) / 256;           // 196
    const int AGG_BLOCKS = (N_NODES + 3) / 4;            // 12500

    // ---- prep ----
    conv_h_zero_kernel<<<HBLK, 256, 0, stream>>>(node_feats, hb0, cnt_d, cnt_g);
    conv_wt3_kernel<<<W3BLK, 256, 0, stream>>>(W1, W2, W3, Wt1, Wt2, Wt3);

    hist2_kernel<<<SORT_BLOCKS, 256, 0, stream>>>(etypes, blk_hist);
    relwave_kernel<<<(N_RELS + 3) / 4, 256, 0, stream>>>(blk_hist, blk_off, rel_tot);
    relbase_kernel<<<1, 128, 0, stream>>>(rel_tot, rel_ptr, tile_base);
    scatter2_kernel<<<SORT_BLOCKS, 256, 0, stream>>>(etypes, src, dst, blk_off, rel_ptr,
                                                     src_s, dst_s);

    histdst_kernel<<<EBLK, 256, 0, stream>>>(dst, cnt_d);
    scanblk_kernel<<<NSCAN_BLKS, SCAN_BLK, 0, stream>>>(cnt_d, row_ptr, blk_tot);
    scantop_kernel<<<1, 64, 0, stream>>>(blk_tot, blk_base);
    scanadd_kernel<<<NSCAN_BLKS, SCAN_BLK, 0, stream>>>(row_ptr, cursor_d, blk_base);
    dpos_kernel<<<EBLK, 256, 0, stream>>>(dst_s, cursor_d, dpos);

    histgid_kernel<<<NBLK256, 256, 0, stream>>>(graph_ids, cnt_g);
    scangid_kernel<<<1, 512, 0, stream>>>(cnt_g, g_ptr);

    // ---- 3 RGCN layers ----
    msg_mfma_kernel<<<MSG_BLOCKS, 256, 0, stream>>>(hb0, Wt1, rel_ptr, tile_base,
                                                    src_s, dpos, msg);
    agg_kernel<<<AGG_BLOCKS, 256, 0, stream>>>(msg, row_ptr, cnt_d, b1, hb1);

    msg_mfma_kernel<<<MSG_BLOCKS, 256, 0, stream>>>(hb1, Wt2, rel_ptr, tile_base,
                                                    src_s, dpos, msg);
    agg_kernel<<<AGG_BLOCKS, 256, 0, stream>>>(msg, row_ptr, cnt_d, b2, hb0);

    msg_mfma_kernel<<<MSG_BLOCKS, 256, 0, stream>>>(hb0, Wt3, rel_ptr, tile_base,
                                                    src_s, dpos, msg);
    agg_kernel<<<AGG_BLOCKS, 256, 0, stream>>>(msg, row_ptr, cnt_d, b3, hb1);

    // ---- fused pool + FC head ----
    poolfc_kernel<<<(N_GRAPHS + 3) / 4, 256, 0, stream>>>(hb1, g_ptr, cnt_g,
                                                          fcW1, fcb1, fcW2, fcb2,
                                                          fcW3, fcb3, pW, pb, out);
}